// Round 4
// baseline (362.564 us; speedup 1.0000x reference)
//
#include <hip/hip_runtime.h>

// MHA forward: inputs fp32, OUTPUT fp32 (reference's output dtype, per stub
// contract). Internals bf16 MFMA. x[2,2048,1024], W[1024,1024], y = x @ W^T.
// Pipeline: (1) QKV gemm (fp32 in -> bf16 ws), (2) causal flash-attention
// (bf16 ws, O aliases Q), (3) O-proj gemm (bf16 A, fp32 W -> fp32 out).

#define DMODEL 1024
#define NHEADS 16
#define DHEAD  64
#define SEQ    2048
#define BATCH  2
#define MROWS  (BATCH * SEQ)   // 4096

typedef __bf16 bf16x8 __attribute__((ext_vector_type(8)));
typedef float  f32x4  __attribute__((ext_vector_type(4)));

__device__ __forceinline__ f32x4 mfma16(bf16x8 a, bf16x8 b, f32x4 c) {
    return __builtin_amdgcn_mfma_f32_16x16x32_bf16(a, b, c, 0, 0, 0);
}

// load 8 contiguous elements as bf16x8 (fp32 source: 2x float4 + cvt)
__device__ __forceinline__ bf16x8 ld8(const float* p) {
    const f32x4 a0 = *(const f32x4*)p;
    const f32x4 a1 = *(const f32x4*)(p + 4);
    bf16x8 v;
    v[0] = (__bf16)a0[0]; v[1] = (__bf16)a0[1];
    v[2] = (__bf16)a0[2]; v[3] = (__bf16)a0[3];
    v[4] = (__bf16)a1[0]; v[5] = (__bf16)a1[1];
    v[6] = (__bf16)a1[2]; v[7] = (__bf16)a1[3];
    return v;
}
__device__ __forceinline__ bf16x8 ld8(const __bf16* p) {
    return *(const bf16x8*)p;
}

// ---------------------------------------------------------------------------
// C[m][n] = sum_k A[m][k] * W[n][k]; A fp32 or bf16, W fp32, C bf16 or fp32.
// 128x128 tile, BK=32, 256 threads (4 waves, each 64x64 = 4x4 MFMA tiles).
// ---------------------------------------------------------------------------
template <typename TA, typename TC>
__device__ __forceinline__ void gemm_bt_body(const TA* __restrict__ A,
                                             const float* __restrict__ W,
                                             TC* __restrict__ C,
                                             int m0, int n0) {
    constexpr int K = DMODEL;
    __shared__ __align__(16) __bf16 As[128][40];  // +8 pad
    __shared__ __align__(16) __bf16 Bs[128][40];

    const int tid  = threadIdx.x;
    const int lane = tid & 63;
    const int wave = tid >> 6;
    const int quad = lane >> 4;
    const int l16  = lane & 15;
    const int wm   = wave & 1;
    const int wn   = wave >> 1;

    f32x4 acc[4][4] = {};

    const int lrow = tid >> 2;         // 0..63 (also +64)
    const int lcol = (tid & 3) * 8;    // 0,8,16,24

    for (int k0 = 0; k0 < K; k0 += 32) {
        __syncthreads();
        *(bf16x8*)(&As[lrow][lcol])      = ld8(A + (size_t)(m0 + lrow)      * K + k0 + lcol);
        *(bf16x8*)(&As[64 + lrow][lcol]) = ld8(A + (size_t)(m0 + 64 + lrow) * K + k0 + lcol);
        *(bf16x8*)(&Bs[lrow][lcol])      = ld8(W + (size_t)(n0 + lrow)      * K + k0 + lcol);
        *(bf16x8*)(&Bs[64 + lrow][lcol]) = ld8(W + (size_t)(n0 + 64 + lrow) * K + k0 + lcol);
        __syncthreads();

        bf16x8 af[4], bfr[4];
#pragma unroll
        for (int i = 0; i < 4; ++i) {
            af[i]  = *(const bf16x8*)(&As[wm * 64 + i * 16 + l16][quad * 8]);
            bfr[i] = *(const bf16x8*)(&Bs[wn * 64 + i * 16 + l16][quad * 8]);
        }
#pragma unroll
        for (int mi = 0; mi < 4; ++mi)
#pragma unroll
            for (int ni = 0; ni < 4; ++ni)
                acc[mi][ni] = mfma16(af[mi], bfr[ni], acc[mi][ni]);
    }

    // C/D layout: col = l16, row = quad*4 + r  [verified m89/m91]
#pragma unroll
    for (int mi = 0; mi < 4; ++mi)
#pragma unroll
        for (int ni = 0; ni < 4; ++ni)
#pragma unroll
            for (int r = 0; r < 4; ++r) {
                int row = m0 + wm * 64 + mi * 16 + quad * 4 + r;
                int col = n0 + wn * 64 + ni * 16 + l16;
                C[(size_t)row * DMODEL + col] = (TC)acc[mi][ni][r];
            }
}

__global__ __launch_bounds__(256) void qkv_kernel(const float* __restrict__ X,
                                                  const float* __restrict__ Wq,
                                                  const float* __restrict__ Wk,
                                                  const float* __restrict__ Wv,
                                                  __bf16* __restrict__ Q,
                                                  __bf16* __restrict__ K,
                                                  __bf16* __restrict__ V) {
    const float* W = (blockIdx.z == 0) ? Wq : (blockIdx.z == 1) ? Wk : Wv;
    __bf16*      Y = (blockIdx.z == 0) ? Q  : (blockIdx.z == 1) ? K  : V;
    gemm_bt_body<float, __bf16>(X, W, Y, blockIdx.y * 128, blockIdx.x * 128);
}

__global__ __launch_bounds__(256) void out_gemm_kernel(const __bf16* __restrict__ A,
                                                       const float* __restrict__ W,
                                                       float* __restrict__ C) {
    gemm_bt_body<__bf16, float>(A, W, C, blockIdx.y * 128, blockIdx.x * 128);
}

// ---------------------------------------------------------------------------
// Causal flash attention. Q/K/V bf16 [B,S,H*Dh] row-major (stride DMODEL).
// Block = 64 Q rows of one (b,h); 4 waves x 16 rows. K-tiles of 32.
// O aliases Q: each block reads only its own rows x head-slice of Q (start)
// and writes O to exactly that region (end); no other block touches it.
// ---------------------------------------------------------------------------
__global__ __launch_bounds__(256) void attn_kernel(const __bf16* __restrict__ Q,
                                                   const __bf16* __restrict__ Kg,
                                                   const __bf16* __restrict__ Vg,
                                                   __bf16* __restrict__ O) {
    const int qt = blockIdx.x;   // 0..31  (64-row q tile)
    const int bh = blockIdx.y;   // 0..31
    const int b = bh >> 4, h = bh & 15;
    const size_t base = (size_t)b * SEQ * DMODEL + (size_t)h * DHEAD;

    const int tid  = threadIdx.x;
    const int lane = tid & 63;
    const int wave = tid >> 6;
    const int quad = lane >> 4;
    const int l16  = lane & 15;

    __shared__ __align__(16) __bf16 Ks[32][72];      // [kk][d], +8 pad
    __shared__ __align__(16) __bf16 Vt[64][40];      // [dh][kk], transposed, +8 pad
    __shared__ __align__(16) __bf16 Ps[4][16][32];   // per-wave P round-trip

    // Q fragments: wave's 16 rows (m=l16, k=quad*8+j), d=0..31 / 32..63
    const int qrow = qt * 64 + wave * 16 + l16;
    const bf16x8 qf0 = *(const bf16x8*)(Q + base + (size_t)qrow * DMODEL + quad * 8);
    const bf16x8 qf1 = *(const bf16x8*)(Q + base + (size_t)qrow * DMODEL + 32 + quad * 8);

    f32x4 oacc[4] = {};           // O[16 x 64]: frag f covers dh = f*16 + l16
    float m_i[4], l_i[4];
#pragma unroll
    for (int r = 0; r < 4; ++r) { m_i[r] = -1e30f; l_i[r] = 0.f; }

    const int ldr = tid >> 3;         // 0..31
    const int ldc = (tid & 7) * 8;    // 0..56

    const int ktiles = qt * 2 + 2;    // covers kk <= qt*64+63
    for (int kt = 0; kt < ktiles; ++kt) {
        const int k0 = kt * 32;
        *(bf16x8*)(&Ks[ldr][ldc]) = *(const bf16x8*)(Kg + base + (size_t)(k0 + ldr) * DMODEL + ldc);
        bf16x8 vv = *(const bf16x8*)(Vg + base + (size_t)(k0 + ldr) * DMODEL + ldc);
#pragma unroll
        for (int i = 0; i < 8; ++i) Vt[ldc + i][ldr] = vv[i];
        __syncthreads();

        // scores S[16 x 32] = Q Kt : two col-halves, each K=64 via 2 MFMAs
        f32x4 s0 = {}, s1 = {};
        const bf16x8 k00 = *(const bf16x8*)(&Ks[l16][quad * 8]);
        const bf16x8 k01 = *(const bf16x8*)(&Ks[l16][32 + quad * 8]);
        const bf16x8 k10 = *(const bf16x8*)(&Ks[16 + l16][quad * 8]);
        const bf16x8 k11 = *(const bf16x8*)(&Ks[16 + l16][32 + quad * 8]);
        s0 = mfma16(qf0, k00, s0); s0 = mfma16(qf1, k01, s0);
        s1 = mfma16(qf0, k10, s1); s1 = mfma16(qf1, k11, s1);

        // online softmax; lane holds rows quad*4+r, cols k0+l16 / k0+16+l16
        const int qg = qt * 64 + wave * 16 + quad * 4;
#pragma unroll
        for (int r = 0; r < 4; ++r) {
            const int qq = qg + r;
            const bool um0 = (k0 + l16      <= qq);
            const bool um1 = (k0 + 16 + l16 <= qq);
            const float v0 = s0[r] * 0.125f;
            const float v1 = s1[r] * 0.125f;
            float mx = fmaxf(um0 ? v0 : -1e30f, um1 ? v1 : -1e30f);
            mx = fmaxf(mx, __shfl_xor(mx, 1));
            mx = fmaxf(mx, __shfl_xor(mx, 2));
            mx = fmaxf(mx, __shfl_xor(mx, 4));
            mx = fmaxf(mx, __shfl_xor(mx, 8));
            const float mnew  = fmaxf(m_i[r], mx);
            const float alpha = __expf(m_i[r] - mnew);
            m_i[r] = mnew;
            const float p0 = um0 ? __expf(v0 - mnew) : 0.f;
            const float p1 = um1 ? __expf(v1 - mnew) : 0.f;
            float rs = p0 + p1;
            rs += __shfl_xor(rs, 1);
            rs += __shfl_xor(rs, 2);
            rs += __shfl_xor(rs, 4);
            rs += __shfl_xor(rs, 8);
            l_i[r] = l_i[r] * alpha + rs;
#pragma unroll
            for (int f = 0; f < 4; ++f) oacc[f][r] *= alpha;
            Ps[wave][quad * 4 + r][l16]      = (__bf16)p0;
            Ps[wave][quad * 4 + r][16 + l16] = (__bf16)p1;
        }
        __syncthreads();  // cross-lane P visibility

        // PV: A = P (m=l16, k=quad*8+j), B = Vt rows (contiguous b128)
        const bf16x8 pf = *(const bf16x8*)(&Ps[wave][l16][quad * 8]);
#pragma unroll
        for (int f = 0; f < 4; ++f) {
            const bf16x8 vf = *(const bf16x8*)(&Vt[f * 16 + l16][quad * 8]);
            oacc[f] = mfma16(pf, vf, oacc[f]);
        }
        __syncthreads();  // Ks/Vt/Ps reads done before next stage
    }

    // epilogue: O = oacc / l
#pragma unroll
    for (int r = 0; r < 4; ++r) {
        const float inv = (l_i[r] > 0.f) ? (1.f / l_i[r]) : 0.f;
#pragma unroll
        for (int f = 0; f < 4; ++f) {
            const int qq = qt * 64 + wave * 16 + quad * 4 + r;
            const int dh = f * 16 + l16;
            O[base + (size_t)qq * DMODEL + dh] = (__bf16)(oacc[f][r] * inv);
        }
    }
}

// ---------------------------------------------------------------------------
extern "C" void kernel_launch(void* const* d_in, const int* in_sizes, int n_in,
                              void* d_out, int out_size, void* d_ws, size_t ws_size,
                              hipStream_t stream) {
    const float* x  = (const float*)d_in[0];
    const float* Wq = (const float*)d_in[1];
    const float* Wk = (const float*)d_in[2];
    const float* Wv = (const float*)d_in[3];
    const float* Wo = (const float*)d_in[4];
    float* out = (float*)d_out;               // fp32 output per reference dtype

    const size_t t = (size_t)MROWS * DMODEL;  // 4M elems = 8 MB bf16
    __bf16* Q = (__bf16*)d_ws;
    __bf16* K = Q + t;
    __bf16* V = K + t;                        // 24 MB total; O aliases Q

    dim3 g1(DMODEL / 128, MROWS / 128, 3);    // 8 x 32 x 3
    qkv_kernel<<<g1, 256, 0, stream>>>(x, Wq, Wk, Wv, Q, K, V);

    dim3 g2(SEQ / 64, BATCH * NHEADS);        // 32 x 32
    attn_kernel<<<g2, 256, 0, stream>>>(Q, K, V, /*O=*/Q);

    dim3 g3(DMODEL / 128, MROWS / 128);       // 8 x 32
    out_gemm_kernel<<<g3, 256, 0, stream>>>(/*O=*/Q, Wo, out);
}

// Round 5
// 234.296 us; speedup vs baseline: 1.5475x; 1.5475x over previous
//
#include <hip/hip_runtime.h>

// MHA forward: inputs fp32, output fp32. Internals bf16 MFMA.
// x[2,2048,1024], W[1024,1024], y = x @ W^T.
// (1) QKV gemm (fp32 in -> bf16 ws), (2) causal flash-attention (S^T/O^T
// formulation, balanced q-tile pairs), (3) O-proj gemm (bf16 A -> fp32 out).

#define DMODEL 1024
#define NHEADS 16
#define DHEAD  64
#define SEQ    2048
#define BATCH  2
#define MROWS  (BATCH * SEQ)   // 4096

typedef __bf16 bf16x8 __attribute__((ext_vector_type(8)));
typedef __bf16 bf16x4 __attribute__((ext_vector_type(4)));
typedef float  f32x4  __attribute__((ext_vector_type(4)));

__device__ __forceinline__ f32x4 mfma16(bf16x8 a, bf16x8 b, f32x4 c) {
    return __builtin_amdgcn_mfma_f32_16x16x32_bf16(a, b, c, 0, 0, 0);
}

__device__ __forceinline__ bf16x8 ld8(const float* p) {
    const f32x4 a0 = *(const f32x4*)p;
    const f32x4 a1 = *(const f32x4*)(p + 4);
    bf16x8 v;
    v[0] = (__bf16)a0[0]; v[1] = (__bf16)a0[1];
    v[2] = (__bf16)a0[2]; v[3] = (__bf16)a0[3];
    v[4] = (__bf16)a1[0]; v[5] = (__bf16)a1[1];
    v[6] = (__bf16)a1[2]; v[7] = (__bf16)a1[3];
    return v;
}
__device__ __forceinline__ bf16x8 ld8(const __bf16* p) {
    return *(const bf16x8*)p;
}

// ---------------------------------------------------------------------------
// GEMM: C[m][n] = sum_k A[m][k] * W[n][k]  (unchanged from round 4)
// ---------------------------------------------------------------------------
template <typename TA, typename TC>
__device__ __forceinline__ void gemm_bt_body(const TA* __restrict__ A,
                                             const float* __restrict__ W,
                                             TC* __restrict__ C,
                                             int m0, int n0) {
    constexpr int K = DMODEL;
    __shared__ __align__(16) __bf16 As[128][40];
    __shared__ __align__(16) __bf16 Bs[128][40];

    const int tid  = threadIdx.x;
    const int lane = tid & 63;
    const int wave = tid >> 6;
    const int quad = lane >> 4;
    const int l16  = lane & 15;
    const int wm   = wave & 1;
    const int wn   = wave >> 1;

    f32x4 acc[4][4] = {};

    const int lrow = tid >> 2;
    const int lcol = (tid & 3) * 8;

    for (int k0 = 0; k0 < K; k0 += 32) {
        __syncthreads();
        *(bf16x8*)(&As[lrow][lcol])      = ld8(A + (size_t)(m0 + lrow)      * K + k0 + lcol);
        *(bf16x8*)(&As[64 + lrow][lcol]) = ld8(A + (size_t)(m0 + 64 + lrow) * K + k0 + lcol);
        *(bf16x8*)(&Bs[lrow][lcol])      = ld8(W + (size_t)(n0 + lrow)      * K + k0 + lcol);
        *(bf16x8*)(&Bs[64 + lrow][lcol]) = ld8(W + (size_t)(n0 + 64 + lrow) * K + k0 + lcol);
        __syncthreads();

        bf16x8 af[4], bfr[4];
#pragma unroll
        for (int i = 0; i < 4; ++i) {
            af[i]  = *(const bf16x8*)(&As[wm * 64 + i * 16 + l16][quad * 8]);
            bfr[i] = *(const bf16x8*)(&Bs[wn * 64 + i * 16 + l16][quad * 8]);
        }
#pragma unroll
        for (int mi = 0; mi < 4; ++mi)
#pragma unroll
            for (int ni = 0; ni < 4; ++ni)
                acc[mi][ni] = mfma16(af[mi], bfr[ni], acc[mi][ni]);
    }

#pragma unroll
    for (int mi = 0; mi < 4; ++mi)
#pragma unroll
        for (int ni = 0; ni < 4; ++ni)
#pragma unroll
            for (int r = 0; r < 4; ++r) {
                int row = m0 + wm * 64 + mi * 16 + quad * 4 + r;
                int col = n0 + wn * 64 + ni * 16 + l16;
                C[(size_t)row * DMODEL + col] = (TC)acc[mi][ni][r];
            }
}

__global__ __launch_bounds__(256) void qkv_kernel(const float* __restrict__ X,
                                                  const float* __restrict__ Wq,
                                                  const float* __restrict__ Wk,
                                                  const float* __restrict__ Wv,
                                                  __bf16* __restrict__ Q,
                                                  __bf16* __restrict__ K,
                                                  __bf16* __restrict__ V) {
    const float* W = (blockIdx.z == 0) ? Wq : (blockIdx.z == 1) ? Wk : Wv;
    __bf16*      Y = (blockIdx.z == 0) ? Q  : (blockIdx.z == 1) ? K  : V;
    gemm_bt_body<float, __bf16>(X, W, Y, blockIdx.y * 128, blockIdx.x * 128);
}

__global__ __launch_bounds__(256) void out_gemm_kernel(const __bf16* __restrict__ A,
                                                       const float* __restrict__ W,
                                                       float* __restrict__ C) {
    gemm_bt_body<__bf16, float>(A, W, C, blockIdx.y * 128, blockIdx.x * 128);
}

// ---------------------------------------------------------------------------
// Causal flash attention, S^T / O^T formulation.
// Block = 128 threads (2 waves x 16 q-rows = 32-row q-tile). Block pr
// processes q-tiles pr and 63-pr: constant 65 K-tiles of 32 per block.
// S^T = mfma(K-frag, Q-frag): C col = q (lane l16), row = kk (quad*4+r)
//   -> softmax state m,l,alpha is ONE scalar per lane; reduce = 2 shfls.
// O^T = mfma(V^T-frag, P^T-frag): C col = q again -> alpha rescale local.
// Vt staged with XOR granule swizzle (kills 8-way write conflicts).
// ---------------------------------------------------------------------------
__global__ __launch_bounds__(128) void attn_kernel(const __bf16* __restrict__ Q,
                                                   const __bf16* __restrict__ Kg,
                                                   const __bf16* __restrict__ Vg,
                                                   __bf16* __restrict__ O) {
    const int pr = blockIdx.x;   // 0..31 (tile pair)
    const int bh = blockIdx.y;   // 0..31
    const int b = bh >> 4, h = bh & 15;
    const size_t base = (size_t)b * SEQ * DMODEL + (size_t)h * DHEAD;

    const int tid  = threadIdx.x;
    const int lane = tid & 63;
    const int wave = tid >> 6;   // 0..1
    const int quad = lane >> 4;
    const int l16  = lane & 15;

    __shared__ __align__(16) __bf16 Ks[32][80];       // [kk][d], stride 160B
    __shared__ __align__(16) __bf16 Vt[64][40];       // [dh][kk-swizzled]
    __shared__ __align__(16) __bf16 Ps[2][16][40];    // per-wave [q][kk]

    // staging assignment: 128 threads, kk row = tid>>2, dh base = (tid&3)*16
    const int ldr = tid >> 2;            // 0..31
    const int c0  = (tid & 3) * 16;      // 0,16,32,48
    // swizzled Vt column base for this thread's dh block (dh>>4 = c0>>4)
    const int vcol = (((ldr >> 3) ^ (c0 >> 4)) << 3) | (ldr & 7);

#pragma unroll
    for (int sel = 0; sel < 2; ++sel) {
        const int qt = sel ? (63 - pr) : pr;       // 32-row q-tile index
        const int qrow = qt * 32 + wave * 16 + l16;

        // Q fragments (B-operand): n = q = l16-row, k = d = quad*8+j
        const bf16x8 qf0 = *(const bf16x8*)(Q + base + (size_t)qrow * DMODEL + quad * 8);
        const bf16x8 qf1 = *(const bf16x8*)(Q + base + (size_t)qrow * DMODEL + 32 + quad * 8);

        f32x4 oacc[4] = {};      // O^T: lane q=l16, dh = f*16 + quad*4 + r
        float m_i = -1e30f, l_i = 0.f;

        const int ktiles = qt + 1;

        // prefetch kt=0
        const __bf16* kp = Kg + base + (size_t)ldr * DMODEL + c0;
        const __bf16* vp = Vg + base + (size_t)ldr * DMODEL + c0;
        bf16x8 pk0 = *(const bf16x8*)(kp);
        bf16x8 pk1 = *(const bf16x8*)(kp + 8);
        bf16x8 pv0 = *(const bf16x8*)(vp);
        bf16x8 pv1 = *(const bf16x8*)(vp + 8);

        for (int kt = 0; kt < ktiles; ++kt) {
            // stage current K/V tile
            *(bf16x8*)(&Ks[ldr][c0])     = pk0;
            *(bf16x8*)(&Ks[ldr][c0 + 8]) = pk1;
#pragma unroll
            for (int i = 0; i < 8; ++i) {
                Vt[c0 + i][vcol]     = pv0[i];
                Vt[c0 + 8 + i][vcol] = pv1[i];
            }
            __syncthreads();

            // prefetch next tile (latency overlaps compute below)
            if (kt + 1 < ktiles) {
                const __bf16* kp2 = Kg + base + (size_t)((kt + 1) * 32 + ldr) * DMODEL + c0;
                const __bf16* vp2 = Vg + base + (size_t)((kt + 1) * 32 + ldr) * DMODEL + c0;
                pk0 = *(const bf16x8*)(kp2);
                pk1 = *(const bf16x8*)(kp2 + 8);
                pv0 = *(const bf16x8*)(vp2);
                pv1 = *(const bf16x8*)(vp2 + 8);
            }

            const int k0 = kt * 32;

            // S^T[kk][q]: A = K rows (m=kk-local), B = Q^T (n=q)
            const bf16x8 kf00 = *(const bf16x8*)(&Ks[l16][quad * 8]);
            const bf16x8 kf01 = *(const bf16x8*)(&Ks[l16][32 + quad * 8]);
            const bf16x8 kf10 = *(const bf16x8*)(&Ks[16 + l16][quad * 8]);
            const bf16x8 kf11 = *(const bf16x8*)(&Ks[16 + l16][32 + quad * 8]);
            f32x4 s0 = {}, s1 = {};
            s0 = mfma16(kf00, qf0, s0); s0 = mfma16(kf01, qf1, s0);
            s1 = mfma16(kf10, qf0, s1); s1 = mfma16(kf11, qf1, s1);
            // lane holds S^T[k0 + h*16 + quad*4 + r][qrow], h=0 (s0), h=1 (s1)

            // online softmax: one scalar state per lane (q = l16 row)
            float sc[2][4];
            bool  ok[2][4];
            float mx = -1e30f;
#pragma unroll
            for (int hh = 0; hh < 2; ++hh)
#pragma unroll
                for (int r = 0; r < 4; ++r) {
                    const int kk = k0 + hh * 16 + quad * 4 + r;
                    const float v = (hh ? s1[r] : s0[r]) * 0.125f;
                    sc[hh][r] = v;
                    ok[hh][r] = (kk <= qrow);
                    mx = fmaxf(mx, ok[hh][r] ? v : -1e30f);
                }
            mx = fmaxf(mx, __shfl_xor(mx, 16));
            mx = fmaxf(mx, __shfl_xor(mx, 32));
            const float mnew  = fmaxf(m_i, mx);
            const float alpha = __expf(m_i - mnew);
            m_i = mnew;

            float p[2][4];
            float rs = 0.f;
#pragma unroll
            for (int hh = 0; hh < 2; ++hh)
#pragma unroll
                for (int r = 0; r < 4; ++r) {
                    p[hh][r] = ok[hh][r] ? __expf(sc[hh][r] - mnew) : 0.f;
                    rs += p[hh][r];
                }
            rs += __shfl_xor(rs, 16);
            rs += __shfl_xor(rs, 32);
            l_i = l_i * alpha + rs;

            // P^T -> LDS (wave-private; same-wave ds ordering via lgkmcnt)
            bf16x4 w0, w1;
#pragma unroll
            for (int r = 0; r < 4; ++r) { w0[r] = (__bf16)p[0][r]; w1[r] = (__bf16)p[1][r]; }
            *(bf16x4*)(&Ps[wave][l16][quad * 4])      = w0;
            *(bf16x4*)(&Ps[wave][l16][16 + quad * 4]) = w1;

            // O^T += V^T P^T : A = V^T (m=dh), B = P^T (n=q)
            const bf16x8 pf = *(const bf16x8*)(&Ps[wave][l16][quad * 8]);
#pragma unroll
            for (int f = 0; f < 4; ++f) {
                const bf16x8 vf = *(const bf16x8*)(&Vt[f * 16 + l16][(quad ^ f) * 8]);
                oacc[f] = mfma16(vf, pf, oacc[f] * alpha);
            }
            __syncthreads();  // Ks/Vt reads done before next staging
        }

        // epilogue: O[qrow][dh] = oacc / l ; dh = f*16 + quad*4 + r
        const float inv = (l_i > 0.f) ? (1.f / l_i) : 0.f;
#pragma unroll
        for (int f = 0; f < 4; ++f) {
            bf16x4 o;
#pragma unroll
            for (int r = 0; r < 4; ++r) o[r] = (__bf16)(oacc[f][r] * inv);
            *(bf16x4*)(O + base + (size_t)qrow * DMODEL + f * 16 + quad * 4) = o;
        }
    }
}

// ---------------------------------------------------------------------------
extern "C" void kernel_launch(void* const* d_in, const int* in_sizes, int n_in,
                              void* d_out, int out_size, void* d_ws, size_t ws_size,
                              hipStream_t stream) {
    const float* x  = (const float*)d_in[0];
    const float* Wq = (const float*)d_in[1];
    const float* Wk = (const float*)d_in[2];
    const float* Wv = (const float*)d_in[3];
    const float* Wo = (const float*)d_in[4];
    float* out = (float*)d_out;

    const size_t t = (size_t)MROWS * DMODEL;  // 8 MB bf16 each
    __bf16* Q = (__bf16*)d_ws;
    __bf16* K = Q + t;
    __bf16* V = K + t;                        // 24 MB; O aliases Q

    dim3 g1(DMODEL / 128, MROWS / 128, 3);
    qkv_kernel<<<g1, 256, 0, stream>>>(x, Wq, Wk, Wv, Q, K, V);

    dim3 g2(SEQ / 64, BATCH * NHEADS);        // 32 pairs x 32 bh
    attn_kernel<<<g2, 128, 0, stream>>>(Q, K, V, /*O=*/Q);

    dim3 g3(DMODEL / 128, MROWS / 128);
    out_gemm_kernel<<<g3, 256, 0, stream>>>(/*O=*/Q, Wo, out);
}

// Round 6
// 220.723 us; speedup vs baseline: 1.6426x; 1.0615x over previous
//
#include <hip/hip_runtime.h>

// MHA forward: inputs fp32, output fp32. Internals bf16 MFMA.
// (0) cvt fp32->bf16 (x + 4 W's), (1) QKV gemm (pure bf16, global_load_lds),
// (2) causal flash-attention (S^T/O^T), (3) O-proj gemm (bf16 -> fp32 out).

#define DMODEL 1024
#define NHEADS 16
#define DHEAD  64
#define SEQ    2048
#define BATCH  2
#define MROWS  (BATCH * SEQ)   // 4096

typedef __bf16 bf16x8 __attribute__((ext_vector_type(8)));
typedef __bf16 bf16x4 __attribute__((ext_vector_type(4)));
typedef float  f32x4  __attribute__((ext_vector_type(4)));

__device__ __forceinline__ f32x4 mfma16(bf16x8 a, bf16x8 b, f32x4 c) {
    return __builtin_amdgcn_mfma_f32_16x16x32_bf16(a, b, c, 0, 0, 0);
}

__device__ __forceinline__ bf16x8 ld8(const float* p) {
    const f32x4 a0 = *(const f32x4*)p;
    const f32x4 a1 = *(const f32x4*)(p + 4);
    bf16x8 v;
    v[0] = (__bf16)a0[0]; v[1] = (__bf16)a0[1];
    v[2] = (__bf16)a0[2]; v[3] = (__bf16)a0[3];
    v[4] = (__bf16)a1[0]; v[5] = (__bf16)a1[1];
    v[6] = (__bf16)a1[2]; v[7] = (__bf16)a1[3];
    return v;
}

// async global->LDS, 16 B per lane; LDS dest = wave-uniform base + lane*16
__device__ __forceinline__ void gll16(const __bf16* g, __bf16* l) {
    __builtin_amdgcn_global_load_lds(
        (const __attribute__((address_space(1))) void*)g,
        (__attribute__((address_space(3))) void*)l,
        16, 0, 0);
}

// ---------------------------------------------------------------------------
// fp32 -> bf16 conversion pass. y=0: x (4M elems); y=1..4: W's -> wcat.
// ---------------------------------------------------------------------------
__global__ __launch_bounds__(256) void cvt_kernel(const float* __restrict__ x,
                                                  const float* __restrict__ Wq,
                                                  const float* __restrict__ Wk,
                                                  const float* __restrict__ Wv,
                                                  const float* __restrict__ Wo,
                                                  __bf16* __restrict__ xb,
                                                  __bf16* __restrict__ wcat) {
    const int y = blockIdx.y;
    const float* src;
    __bf16* dst;
    int nchunks;
    if (y == 0) { src = x; dst = xb; nchunks = (MROWS * DMODEL) / 8; }
    else {
        src = (y == 1) ? Wq : (y == 2) ? Wk : (y == 3) ? Wv : Wo;
        dst = wcat + (size_t)(y - 1) * DMODEL * DMODEL;
        nchunks = (DMODEL * DMODEL) / 8;
    }
    const int c = blockIdx.x * 256 + threadIdx.x;
    if (c < nchunks) *(bf16x8*)(dst + (size_t)c * 8) = ld8(src + (size_t)c * 8);
}

// ---------------------------------------------------------------------------
// Pure-bf16 GEMM: C[m][n] = sum_k A[m][k] * W[n][k].
// 128x128 tile, BK=32, 256 threads, m97 structure: global_load_lds width=16
// into UNPADDED LDS (layout = lane order, per m104/m108 constraint).
// ---------------------------------------------------------------------------
template <typename TC>
__device__ __forceinline__ void gemm_bb_body(const __bf16* __restrict__ A,
                                             const __bf16* __restrict__ W,
                                             TC* __restrict__ C,
                                             int m0, int n0) {
    constexpr int K = DMODEL;
    __shared__ __align__(16) __bf16 As[128][32];  // NO pad (global_load_lds)
    __shared__ __align__(16) __bf16 Bs[128][32];

    const int tid  = threadIdx.x;
    const int lane = tid & 63;
    const int wave = tid >> 6;
    const int quad = lane >> 4;
    const int l16  = lane & 15;
    const int wm   = wave & 1;
    const int wn   = wave >> 1;

    // staging: lane i of wave w -> LDS row w*16 + i/4, elem col (i&3)*8
    const int srow = lane >> 2;          // 0..15
    const int scol = (lane & 3) * 8;

    const __bf16* a0p = A + (size_t)(m0 + wave * 16 + srow) * K + scol;
    const __bf16* a1p = A + (size_t)(m0 + 64 + wave * 16 + srow) * K + scol;
    const __bf16* b0p = W + (size_t)(n0 + wave * 16 + srow) * K + scol;
    const __bf16* b1p = W + (size_t)(n0 + 64 + wave * 16 + srow) * K + scol;

    f32x4 acc[4][4] = {};

    for (int k0 = 0; k0 < K; k0 += 32) {
        __syncthreads();
        gll16(a0p + k0, &As[wave * 16][0]);
        gll16(a1p + k0, &As[64 + wave * 16][0]);
        gll16(b0p + k0, &Bs[wave * 16][0]);
        gll16(b1p + k0, &Bs[64 + wave * 16][0]);
        __syncthreads();   // drains vmcnt before any LDS read

        bf16x8 af[4], bfr[4];
#pragma unroll
        for (int i = 0; i < 4; ++i) {
            af[i]  = *(const bf16x8*)(&As[wm * 64 + i * 16 + l16][quad * 8]);
            bfr[i] = *(const bf16x8*)(&Bs[wn * 64 + i * 16 + l16][quad * 8]);
        }
#pragma unroll
        for (int mi = 0; mi < 4; ++mi)
#pragma unroll
            for (int ni = 0; ni < 4; ++ni)
                acc[mi][ni] = mfma16(af[mi], bfr[ni], acc[mi][ni]);
    }

    // C/D layout: col = l16, row = quad*4 + r
#pragma unroll
    for (int mi = 0; mi < 4; ++mi)
#pragma unroll
        for (int ni = 0; ni < 4; ++ni)
#pragma unroll
            for (int r = 0; r < 4; ++r) {
                int row = m0 + wm * 64 + mi * 16 + quad * 4 + r;
                int col = n0 + wn * 64 + ni * 16 + l16;
                C[(size_t)row * DMODEL + col] = (TC)acc[mi][ni][r];
            }
}

__global__ __launch_bounds__(256) void qkv_kernel(const __bf16* __restrict__ X,
                                                  const __bf16* __restrict__ wcat,
                                                  __bf16* __restrict__ QKV) {
    const __bf16* W = wcat + (size_t)blockIdx.z * DMODEL * DMODEL;
    __bf16*       Y = QKV + (size_t)blockIdx.z * MROWS * DMODEL;
    gemm_bb_body<__bf16>(X, W, Y, blockIdx.y * 128, blockIdx.x * 128);
}

__global__ __launch_bounds__(256) void out_gemm_kernel(const __bf16* __restrict__ A,
                                                       const __bf16* __restrict__ W,
                                                       float* __restrict__ C) {
    gemm_bb_body<float>(A, W, C, blockIdx.y * 128, blockIdx.x * 128);
}

// ---------------------------------------------------------------------------
// Causal flash attention, S^T / O^T formulation (unchanged from round 5).
// ---------------------------------------------------------------------------
__global__ __launch_bounds__(128) void attn_kernel(const __bf16* __restrict__ Q,
                                                   const __bf16* __restrict__ Kg,
                                                   const __bf16* __restrict__ Vg,
                                                   __bf16* __restrict__ O) {
    const int pr = blockIdx.x;   // 0..31 (tile pair)
    const int bh = blockIdx.y;   // 0..31
    const int b = bh >> 4, h = bh & 15;
    const size_t base = (size_t)b * SEQ * DMODEL + (size_t)h * DHEAD;

    const int tid  = threadIdx.x;
    const int lane = tid & 63;
    const int wave = tid >> 6;
    const int quad = lane >> 4;
    const int l16  = lane & 15;

    __shared__ __align__(16) __bf16 Ks[32][80];
    __shared__ __align__(16) __bf16 Vt[64][40];
    __shared__ __align__(16) __bf16 Ps[2][16][40];

    const int ldr = tid >> 2;
    const int c0  = (tid & 3) * 16;
    const int vcol = (((ldr >> 3) ^ (c0 >> 4)) << 3) | (ldr & 7);

#pragma unroll
    for (int sel = 0; sel < 2; ++sel) {
        const int qt = sel ? (63 - pr) : pr;
        const int qrow = qt * 32 + wave * 16 + l16;

        const bf16x8 qf0 = *(const bf16x8*)(Q + base + (size_t)qrow * DMODEL + quad * 8);
        const bf16x8 qf1 = *(const bf16x8*)(Q + base + (size_t)qrow * DMODEL + 32 + quad * 8);

        f32x4 oacc[4] = {};
        float m_i = -1e30f, l_i = 0.f;

        const int ktiles = qt + 1;

        const __bf16* kp = Kg + base + (size_t)ldr * DMODEL + c0;
        const __bf16* vp = Vg + base + (size_t)ldr * DMODEL + c0;
        bf16x8 pk0 = *(const bf16x8*)(kp);
        bf16x8 pk1 = *(const bf16x8*)(kp + 8);
        bf16x8 pv0 = *(const bf16x8*)(vp);
        bf16x8 pv1 = *(const bf16x8*)(vp + 8);

        for (int kt = 0; kt < ktiles; ++kt) {
            *(bf16x8*)(&Ks[ldr][c0])     = pk0;
            *(bf16x8*)(&Ks[ldr][c0 + 8]) = pk1;
#pragma unroll
            for (int i = 0; i < 8; ++i) {
                Vt[c0 + i][vcol]     = pv0[i];
                Vt[c0 + 8 + i][vcol] = pv1[i];
            }
            __syncthreads();

            if (kt + 1 < ktiles) {
                const __bf16* kp2 = Kg + base + (size_t)((kt + 1) * 32 + ldr) * DMODEL + c0;
                const __bf16* vp2 = Vg + base + (size_t)((kt + 1) * 32 + ldr) * DMODEL + c0;
                pk0 = *(const bf16x8*)(kp2);
                pk1 = *(const bf16x8*)(kp2 + 8);
                pv0 = *(const bf16x8*)(vp2);
                pv1 = *(const bf16x8*)(vp2 + 8);
            }

            const int k0 = kt * 32;

            const bf16x8 kf00 = *(const bf16x8*)(&Ks[l16][quad * 8]);
            const bf16x8 kf01 = *(const bf16x8*)(&Ks[l16][32 + quad * 8]);
            const bf16x8 kf10 = *(const bf16x8*)(&Ks[16 + l16][quad * 8]);
            const bf16x8 kf11 = *(const bf16x8*)(&Ks[16 + l16][32 + quad * 8]);
            f32x4 s0 = {}, s1 = {};
            s0 = mfma16(kf00, qf0, s0); s0 = mfma16(kf01, qf1, s0);
            s1 = mfma16(kf10, qf0, s1); s1 = mfma16(kf11, qf1, s1);

            float sc[2][4];
            bool  ok[2][4];
            float mx = -1e30f;
#pragma unroll
            for (int hh = 0; hh < 2; ++hh)
#pragma unroll
                for (int r = 0; r < 4; ++r) {
                    const int kk = k0 + hh * 16 + quad * 4 + r;
                    const float v = (hh ? s1[r] : s0[r]) * 0.125f;
                    sc[hh][r] = v;
                    ok[hh][r] = (kk <= qrow);
                    mx = fmaxf(mx, ok[hh][r] ? v : -1e30f);
                }
            mx = fmaxf(mx, __shfl_xor(mx, 16));
            mx = fmaxf(mx, __shfl_xor(mx, 32));
            const float mnew  = fmaxf(m_i, mx);
            const float alpha = __expf(m_i - mnew);
            m_i = mnew;

            float p[2][4];
            float rs = 0.f;
#pragma unroll
            for (int hh = 0; hh < 2; ++hh)
#pragma unroll
                for (int r = 0; r < 4; ++r) {
                    p[hh][r] = ok[hh][r] ? __expf(sc[hh][r] - mnew) : 0.f;
                    rs += p[hh][r];
                }
            rs += __shfl_xor(rs, 16);
            rs += __shfl_xor(rs, 32);
            l_i = l_i * alpha + rs;

            bf16x4 w0, w1;
#pragma unroll
            for (int r = 0; r < 4; ++r) { w0[r] = (__bf16)p[0][r]; w1[r] = (__bf16)p[1][r]; }
            *(bf16x4*)(&Ps[wave][l16][quad * 4])      = w0;
            *(bf16x4*)(&Ps[wave][l16][16 + quad * 4]) = w1;

            const bf16x8 pf = *(const bf16x8*)(&Ps[wave][l16][quad * 8]);
#pragma unroll
            for (int f = 0; f < 4; ++f) {
                const bf16x8 vf = *(const bf16x8*)(&Vt[f * 16 + l16][(quad ^ f) * 8]);
                oacc[f] = mfma16(vf, pf, oacc[f] * alpha);
            }
            __syncthreads();
        }

        const float inv = (l_i > 0.f) ? (1.f / l_i) : 0.f;
#pragma unroll
        for (int f = 0; f < 4; ++f) {
            bf16x4 o;
#pragma unroll
            for (int r = 0; r < 4; ++r) o[r] = (__bf16)(oacc[f][r] * inv);
            *(bf16x4*)(O + base + (size_t)qrow * DMODEL + f * 16 + quad * 4) = o;
        }
    }
}

// ---------------------------------------------------------------------------
extern "C" void kernel_launch(void* const* d_in, const int* in_sizes, int n_in,
                              void* d_out, int out_size, void* d_ws, size_t ws_size,
                              hipStream_t stream) {
    const float* x  = (const float*)d_in[0];
    const float* Wq = (const float*)d_in[1];
    const float* Wk = (const float*)d_in[2];
    const float* Wv = (const float*)d_in[3];
    const float* Wo = (const float*)d_in[4];
    float* out = (float*)d_out;

    const size_t tm = (size_t)MROWS * DMODEL;    // 4M elems
    const size_t tw = (size_t)DMODEL * DMODEL;   // 1M elems
    __bf16* xb   = (__bf16*)d_ws;                // 4M
    __bf16* wcat = xb + tm;                      // 4M (Wq,Wk,Wv,Wo)
    __bf16* QKV  = wcat + 4 * tw;                // 12M (Q,K,V)
    __bf16* Q = QKV;
    __bf16* K = QKV + tm;
    __bf16* V = QKV + 2 * tm;                    // total 20M elems = 40 MB

    dim3 gc(2048, 5);
    cvt_kernel<<<gc, 256, 0, stream>>>(x, Wq, Wk, Wv, Wo, xb, wcat);

    dim3 g1(DMODEL / 128, MROWS / 128, 3);
    qkv_kernel<<<g1, 256, 0, stream>>>(xb, wcat, QKV);

    dim3 g2(SEQ / 64, BATCH * NHEADS);
    attn_kernel<<<g2, 128, 0, stream>>>(Q, K, V, /*O=*/Q);

    dim3 g3(DMODEL / 128, MROWS / 128);
    out_gemm_kernel<<<g3, 256, 0, stream>>>(/*O=*/Q, wcat + 3 * tw, out);
}